// Round 5
// baseline (323.882 us; speedup 1.0000x reference)
//
#include <hip/hip_runtime.h>
#include <hip/hip_bf16.h>
#include <stdint.h>

#define TOKENS 8192
#define IN_F   4096
#define OUT_F  4096

typedef __attribute__((ext_vector_type(4))) float  f32x4;
typedef __attribute__((ext_vector_type(8))) __bf16 bf16x8;

__device__ __forceinline__ unsigned short f2bf(float f) {
    union { float f; uint32_t u; } c; c.f = f;
    uint32_t u = c.u;
    u += 0x7fffu + ((u >> 16) & 1);   // round-to-nearest-even
    return (unsigned short)(u >> 16);
}

__device__ __forceinline__ void load_lds_16(const void* gptr, void* lptr) {
    __builtin_amdgcn_global_load_lds(
        (const __attribute__((address_space(1))) unsigned int*)gptr,
        (__attribute__((address_space(3))) unsigned int*)lptr, 16, 0, 0);
}

template<int N> __device__ __forceinline__ void vm_bar() {
    if constexpr (N == 3) asm volatile("s_waitcnt vmcnt(3)\ns_barrier" ::: "memory");
    else                  asm volatile("s_waitcnt vmcnt(0)\ns_barrier" ::: "memory");
}

// ---------------- prep: x fp32 -> bf16 ----------------
__global__ __launch_bounds__(256) void cvt_x_kernel(const float* __restrict__ x,
                                                    unsigned short* __restrict__ xb, int n4) {
    int i = blockIdx.x * blockDim.x + threadIdx.x;
    int stride = gridDim.x * blockDim.x;
    for (; i < n4; i += stride) {
        float4 v = ((const float4*)x)[i];
        ushort4 o;
        o.x = f2bf(v.x); o.y = f2bf(v.y); o.z = f2bf(v.z); o.w = f2bf(v.w);
        ((ushort4*)xb)[i] = o;
    }
}

// ---------------- prep: W_eff = W*(1+mask) fp32 -> bf16 ----------------
__global__ __launch_bounds__(256) void cvt_w_kernel(const float* __restrict__ w,
                                                    const int* __restrict__ mask,
                                                    unsigned short* __restrict__ wb) {
    const int n4 = OUT_F * IN_F / 4;
    int i = blockIdx.x * blockDim.x + threadIdx.x;
    int stride = gridDim.x * blockDim.x;
    for (; i < n4; i += stride) {
        int elem = i * 4;
        int o = elem >> 12;
        int k = elem & (IN_F - 1);
        int mb = mask[(o >> 4) * (IN_F / 16) + (k >> 4)];
        float s = mb ? 2.0f : 1.0f;
        float4 v = ((const float4*)w)[i];
        ushort4 ov;
        ov.x = f2bf(v.x * s); ov.y = f2bf(v.y * s);
        ov.z = f2bf(v.z * s); ov.w = f2bf(v.w * s);
        ((ushort4*)wb)[i] = ov;
    }
}

// ------- 128x256 8-wave BK=32, triple-buffered, 2 blocks/CU -------
// LDS (shorts): buf b at b*12288; A tile 128x32 at +0, B tile 256x32 at +4096.
// Swizzle: 8-short chunk c XOR (row>>1)&3 (pre-swizzled global src on stage,
// same XOR on fragment read) -> conflict-free ds_read_b128.
#define BM 128
#define BN 256
#define BK 32
#define NTI (IN_F / BK)   // 128
#define BUF_SH 12288

#define ST(T, OFF) {                                                           \
    const unsigned short* sA_  = srcA  + (size_t)(T) * BK;                     \
    const unsigned short* sB0_ = srcB0 + (size_t)(T) * BK;                     \
    const unsigned short* sB1_ = srcB1 + (size_t)(T) * BK;                     \
    unsigned short* d_ = sm + (OFF) + dstL;                                    \
    load_lds_16(sA_,  d_);                                                     \
    load_lds_16(sB0_, d_ + 4096);                                              \
    load_lds_16(sB1_, d_ + 8192); }

#define COMPUTE(OFF) {                                                         \
    const unsigned short* pA_ = sm + (OFF) + a_base;                           \
    const unsigned short* pB_ = sm + (OFF) + b_base;                           \
    bf16x8 a0 = *(const bf16x8*)(pA_);                                         \
    bf16x8 a1 = *(const bf16x8*)(pA_ + 512);                                   \
    bf16x8 a2 = *(const bf16x8*)(pA_ + 1024);                                  \
    bf16x8 a3 = *(const bf16x8*)(pA_ + 1536);                                  \
    bf16x8 b0 = *(const bf16x8*)(pB_);                                         \
    bf16x8 b1 = *(const bf16x8*)(pB_ + 512);                                   \
    bf16x8 b2 = *(const bf16x8*)(pB_ + 1024);                                  \
    bf16x8 b3 = *(const bf16x8*)(pB_ + 1536);                                  \
    __builtin_amdgcn_s_setprio(1);                                             \
    acc[0][0] = __builtin_amdgcn_mfma_f32_16x16x32_bf16(a0, b0, acc[0][0], 0, 0, 0); \
    acc[0][1] = __builtin_amdgcn_mfma_f32_16x16x32_bf16(a0, b1, acc[0][1], 0, 0, 0); \
    acc[0][2] = __builtin_amdgcn_mfma_f32_16x16x32_bf16(a0, b2, acc[0][2], 0, 0, 0); \
    acc[0][3] = __builtin_amdgcn_mfma_f32_16x16x32_bf16(a0, b3, acc[0][3], 0, 0, 0); \
    acc[1][0] = __builtin_amdgcn_mfma_f32_16x16x32_bf16(a1, b0, acc[1][0], 0, 0, 0); \
    acc[1][1] = __builtin_amdgcn_mfma_f32_16x16x32_bf16(a1, b1, acc[1][1], 0, 0, 0); \
    acc[1][2] = __builtin_amdgcn_mfma_f32_16x16x32_bf16(a1, b2, acc[1][2], 0, 0, 0); \
    acc[1][3] = __builtin_amdgcn_mfma_f32_16x16x32_bf16(a1, b3, acc[1][3], 0, 0, 0); \
    acc[2][0] = __builtin_amdgcn_mfma_f32_16x16x32_bf16(a2, b0, acc[2][0], 0, 0, 0); \
    acc[2][1] = __builtin_amdgcn_mfma_f32_16x16x32_bf16(a2, b1, acc[2][1], 0, 0, 0); \
    acc[2][2] = __builtin_amdgcn_mfma_f32_16x16x32_bf16(a2, b2, acc[2][2], 0, 0, 0); \
    acc[2][3] = __builtin_amdgcn_mfma_f32_16x16x32_bf16(a2, b3, acc[2][3], 0, 0, 0); \
    acc[3][0] = __builtin_amdgcn_mfma_f32_16x16x32_bf16(a3, b0, acc[3][0], 0, 0, 0); \
    acc[3][1] = __builtin_amdgcn_mfma_f32_16x16x32_bf16(a3, b1, acc[3][1], 0, 0, 0); \
    acc[3][2] = __builtin_amdgcn_mfma_f32_16x16x32_bf16(a3, b2, acc[3][2], 0, 0, 0); \
    acc[3][3] = __builtin_amdgcn_mfma_f32_16x16x32_bf16(a3, b3, acc[3][3], 0, 0, 0); \
    __builtin_amdgcn_s_setprio(0); }

__global__ __launch_bounds__(512, 4) void gemm_kernel(const unsigned short* __restrict__ A,
                                                      const unsigned short* __restrict__ B,
                                                      const float* __restrict__ bias,
                                                      float* __restrict__ C) {
    extern __shared__ __align__(16) unsigned short sm[];   // 72KB dynamic

    const int tid  = threadIdx.x;
    const int lane = tid & 63;
    const int wid  = tid >> 6;
    const int wr   = wid >> 2;       // 0..1 -> 64-row span
    const int wc   = wid & 3;        // 0..3 -> 64-col span

    const int nwg = (TOKENS / BM) * (OUT_F / BN);   // 1024, %8==0
    int bid = blockIdx.x;
    int swz = (bid & 7) * (nwg >> 3) + (bid >> 3);  // XCD-aware swizzle
    const int tiles_n = OUT_F / BN;                 // 16
    const int t0 = (swz / tiles_n) * BM;
    const int o0 = (swz % tiles_n) * BN;

    // ---- staging constants (pre-swizzled global source, wave-linear dest) ----
    const int srow = tid >> 2;                      // 0..127
    const int sc   = tid & 3;                       // 8-short chunk
    const int scs  = sc ^ ((srow >> 1) & 3);
    const unsigned short* srcA  = A + (size_t)(t0 + srow) * IN_F + scs * 8;
    const unsigned short* srcB0 = B + (size_t)(o0 + srow) * IN_F + scs * 8;
    const unsigned short* srcB1 = B + (size_t)(o0 + 128 + srow) * IN_F + scs * 8;
    const int dstL = srow * 32 + sc * 8;

    // ---- fragment-read bases (shorts), same swizzle ----
    const int l15 = lane & 15, q = lane >> 4;
    const int qe = q ^ ((l15 >> 1) & 3);
    const int a_base = (wr * 64 + l15) * 32 + qe * 8;          // + mf*512
    const int b_base = 4096 + (wc * 64 + l15) * 32 + qe * 8;   // + nf*512

    f32x4 acc[4][4];
#pragma unroll
    for (int i = 0; i < 4; ++i)
#pragma unroll
        for (int j = 0; j < 4; ++j) acc[i][j] = (f32x4)0.0f;

    // ---- prologue: depth-2 prefetch (6 loads in flight) ----
    ST(0, 0)
    ST(1, BUF_SH)

    int oc = 0, o1 = BUF_SH, o2 = 2 * BUF_SH;
#pragma unroll 3
    for (int T = 0; T < NTI - 2; ++T) {
        vm_bar<3>();       // my tile-T loads landed (T+1's 3 in flight); all waves aligned
        ST(T + 2, o2)      // stage into buffer holding T-1 (reads done, proven by barrier)
        COMPUTE(oc)
        int t_ = oc; oc = o1; o1 = o2; o2 = t_;
    }
    vm_bar<3>();           // tile NTI-2 landed (NTI-1's 3 in flight)
    COMPUTE(oc)
    { int t_ = oc; oc = o1; o1 = o2; o2 = t_; }
    vm_bar<0>();           // tile NTI-1 landed
    COMPUTE(oc)

    // ---- epilogue: C/D layout col = lane&15, row = (lane>>4)*4 + reg ----
    float bv[4];
#pragma unroll
    for (int nf = 0; nf < 4; ++nf) bv[nf] = bias[o0 + wc * 64 + nf * 16 + l15];
#pragma unroll
    for (int mf = 0; mf < 4; ++mf) {
        const int t = t0 + wr * 64 + mf * 16 + q * 4;
#pragma unroll
        for (int nf = 0; nf < 4; ++nf) {
            const int o = o0 + wc * 64 + nf * 16 + l15;
#pragma unroll
            for (int r = 0; r < 4; ++r)
                C[(size_t)(t + r) * OUT_F + o] = acc[mf][nf][r] + bv[nf];
        }
    }
}

// ---------------- fp32 fallback (only if ws too small) ----------------
__global__ __launch_bounds__(256) void gemm_f32_fallback(const float* __restrict__ x,
                                                         const float* __restrict__ w,
                                                         const float* __restrict__ bias,
                                                         const int* __restrict__ mask,
                                                         float* __restrict__ out) {
    __shared__ float As[64][17];
    __shared__ float Bs[64][17];
    int bid = blockIdx.x;
    const int tiles_n = OUT_F / 64;
    int tm = bid / tiles_n, tn = bid % tiles_n;
    int t0 = tm * 64, o0 = tn * 64;
    int tid = threadIdx.x;
    int tx = tid & 15, ty = tid >> 4;
    int lrow = tid >> 2, lc4 = (tid & 3) * 4;
    float acc[4][4] = {};
    for (int k0 = 0; k0 < IN_F; k0 += 16) {
        float4 av = *(const float4*)&x[(size_t)(t0 + lrow) * IN_F + k0 + lc4];
        float4 bv = *(const float4*)&w[(size_t)(o0 + lrow) * IN_F + k0 + lc4];
        int mb = mask[((o0 + lrow) >> 4) * (IN_F / 16) + ((k0 + lc4) >> 4)];
        float s = mb ? 2.0f : 1.0f;
        As[lrow][lc4 + 0] = av.x; As[lrow][lc4 + 1] = av.y;
        As[lrow][lc4 + 2] = av.z; As[lrow][lc4 + 3] = av.w;
        Bs[lrow][lc4 + 0] = bv.x * s; Bs[lrow][lc4 + 1] = bv.y * s;
        Bs[lrow][lc4 + 2] = bv.z * s; Bs[lrow][lc4 + 3] = bv.w * s;
        __syncthreads();
#pragma unroll
        for (int kk = 0; kk < 16; ++kk) {
            float av2[4], bv2[4];
#pragma unroll
            for (int i = 0; i < 4; ++i) av2[i] = As[ty * 4 + i][kk];
#pragma unroll
            for (int j = 0; j < 4; ++j) bv2[j] = Bs[tx * 4 + j][kk];
#pragma unroll
            for (int i = 0; i < 4; ++i)
#pragma unroll
                for (int j = 0; j < 4; ++j) acc[i][j] += av2[i] * bv2[j];
        }
        __syncthreads();
    }
#pragma unroll
    for (int j = 0; j < 4; ++j) {
        int o = o0 + tx * 4 + j;
        float bv = bias[o];
#pragma unroll
        for (int i = 0; i < 4; ++i)
            out[(size_t)(t0 + ty * 4 + i) * OUT_F + o] = acc[i][j] + bv;
    }
}

extern "C" void kernel_launch(void* const* d_in, const int* in_sizes, int n_in,
                              void* d_out, int out_size, void* d_ws, size_t ws_size,
                              hipStream_t stream) {
    const float* x    = (const float*)d_in[0];
    const float* wgt  = (const float*)d_in[1];
    const float* bias = (const float*)d_in[2];
    const int*   mask = (const int*)d_in[3];
    float* out = (float*)d_out;

    size_t xb_bytes = (size_t)TOKENS * IN_F * 2;
    size_t wb_bytes = (size_t)OUT_F * IN_F * 2;

    if (ws_size >= xb_bytes + wb_bytes) {
        unsigned short* xb = (unsigned short*)d_ws;
        unsigned short* wb = (unsigned short*)((char*)d_ws + xb_bytes);
        hipLaunchKernelGGL(cvt_x_kernel, dim3(2048), dim3(256), 0, stream, x, xb, TOKENS * IN_F / 4);
        hipLaunchKernelGGL(cvt_w_kernel, dim3(1024), dim3(256), 0, stream, wgt, mask, wb);
        (void)hipFuncSetAttribute((const void*)gemm_kernel,
                                  hipFuncAttributeMaxDynamicSharedMemorySize, 73728);
        hipLaunchKernelGGL(gemm_kernel, dim3((TOKENS / BM) * (OUT_F / BN)), dim3(512),
                           73728, stream, xb, wb, bias, out);
    } else {
        hipLaunchKernelGGL(gemm_f32_fallback, dim3((TOKENS / 64) * (OUT_F / 64)), dim3(256), 0, stream,
                           x, wgt, bias, mask, out);
    }
}

// Round 6
// 291.478 us; speedup vs baseline: 1.1112x; 1.1112x over previous
//
#include <hip/hip_runtime.h>
#include <hip/hip_bf16.h>
#include <stdint.h>

#define TOKENS 8192
#define IN_F   4096
#define OUT_F  4096

typedef __attribute__((ext_vector_type(4))) float  f32x4;
typedef __attribute__((ext_vector_type(8))) __bf16 bf16x8;

__device__ __forceinline__ unsigned short f2bf(float f) {
    union { float f; uint32_t u; } c; c.f = f;
    uint32_t u = c.u;
    u += 0x7fffu + ((u >> 16) & 1);   // round-to-nearest-even
    return (unsigned short)(u >> 16);
}

__device__ __forceinline__ void load_lds_16(const void* gptr, void* lptr) {
    __builtin_amdgcn_global_load_lds(
        (const __attribute__((address_space(1))) unsigned int*)gptr,
        (__attribute__((address_space(3))) unsigned int*)lptr, 16, 0, 0);
}

template<int N> __device__ __forceinline__ void vm_bar() {
    if constexpr (N == 4) asm volatile("s_waitcnt vmcnt(4)\ns_barrier" ::: "memory");
    else                  asm volatile("s_waitcnt vmcnt(0)\ns_barrier" ::: "memory");
}
__device__ __forceinline__ void bar() { asm volatile("s_barrier" ::: "memory"); }

// ---------------- merged prep: x->bf16 and W_eff=W*(1+mask)->bf16 ----------------
#define XBLOCKS 2048
#define WBLOCKS 1024
__global__ __launch_bounds__(256) void cvt_kernel(const float* __restrict__ x,
                                                  const float* __restrict__ w,
                                                  const int* __restrict__ mask,
                                                  unsigned short* __restrict__ xb,
                                                  unsigned short* __restrict__ wb) {
    int b = blockIdx.x;
    if (b < XBLOCKS) {
        const int n4 = TOKENS * IN_F / 4;
        int i = b * 256 + threadIdx.x;
        const int stride = XBLOCKS * 256;
        for (; i < n4; i += stride) {
            float4 v = ((const float4*)x)[i];
            ushort4 o;
            o.x = f2bf(v.x); o.y = f2bf(v.y); o.z = f2bf(v.z); o.w = f2bf(v.w);
            ((ushort4*)xb)[i] = o;
        }
    } else {
        const int n4 = OUT_F * IN_F / 4;
        int i = (b - XBLOCKS) * 256 + threadIdx.x;
        const int stride = WBLOCKS * 256;
        for (; i < n4; i += stride) {
            int elem = i * 4;
            int o = elem >> 12;
            int k = elem & (IN_F - 1);
            int mb = mask[(o >> 4) * (IN_F / 16) + (k >> 4)];
            float s = mb ? 2.0f : 1.0f;
            float4 v = ((const float4*)w)[i];
            ushort4 ov;
            ov.x = f2bf(v.x * s); ov.y = f2bf(v.y * s);
            ov.z = f2bf(v.z * s); ov.w = f2bf(v.w * s);
            ((ushort4*)wb)[i] = ov;
        }
    }
}

// ------- 256x256 8-wave, 4 loose phases/K-tile, evenly-spread reads -------
// LDS (shorts): A[buf][ks] at buf*16384 + ks*8192 (256 rows x 32 shorts)
//               B[buf][ks] at 32768 + buf*16384 + ks*8192
// Swizzle: 8-short chunk c XOR (row>>1)&3 (pre-swizzled global source on
// stage, same XOR on fragment read) -> <=2-way banks (free).
#define BM 256
#define BN 256
#define BK 64
#define NT (IN_F / BK)   // 64

#define ST_A(T, H) {                                                           \
    const unsigned short* s_ = srcA + (size_t)(T) * BK + (H) * 32;             \
    unsigned short* d_ = sm + (((T) & 1) * 16384 + (H) * 8192) + dstL;         \
    load_lds_16(s_, d_);                                                       \
    load_lds_16(s_ + (size_t)128 * IN_F, d_ + 4096); }
#define ST_B(T, H) {                                                           \
    const unsigned short* s_ = srcB + (size_t)(T) * BK + (H) * 32;             \
    unsigned short* d_ = sm + (32768 + ((T) & 1) * 16384 + (H) * 8192) + dstL; \
    load_lds_16(s_, d_);                                                       \
    load_lds_16(s_ + (size_t)128 * IN_F, d_ + 4096); }

#define RD_B4(BUF, KS) {                                                       \
    const unsigned short* p_ = sm + 32768 + (BUF) * 16384 + (KS) * 8192 + b_base; \
    bb0 = *(const bf16x8*)(p_);        bb1 = *(const bf16x8*)(p_ + 512);       \
    bb2 = *(const bf16x8*)(p_ + 1024); bb3 = *(const bf16x8*)(p_ + 1536); }

#define RD_A4(BUF, KS, MH) {                                                   \
    const unsigned short* p_ = sm + (BUF) * 16384 + (KS) * 8192 + (MH) * 2048 + a_base; \
    aa0 = *(const bf16x8*)(p_);        aa1 = *(const bf16x8*)(p_ + 512);       \
    aa2 = *(const bf16x8*)(p_ + 1024); aa3 = *(const bf16x8*)(p_ + 1536); }

#define MM16(MH) {                                                             \
    __builtin_amdgcn_s_setprio(1);                                             \
    acc[(MH)*4+0][0] = __builtin_amdgcn_mfma_f32_16x16x32_bf16(aa0, bb0, acc[(MH)*4+0][0], 0, 0, 0); \
    acc[(MH)*4+0][1] = __builtin_amdgcn_mfma_f32_16x16x32_bf16(aa0, bb1, acc[(MH)*4+0][1], 0, 0, 0); \
    acc[(MH)*4+0][2] = __builtin_amdgcn_mfma_f32_16x16x32_bf16(aa0, bb2, acc[(MH)*4+0][2], 0, 0, 0); \
    acc[(MH)*4+0][3] = __builtin_amdgcn_mfma_f32_16x16x32_bf16(aa0, bb3, acc[(MH)*4+0][3], 0, 0, 0); \
    acc[(MH)*4+1][0] = __builtin_amdgcn_mfma_f32_16x16x32_bf16(aa1, bb0, acc[(MH)*4+1][0], 0, 0, 0); \
    acc[(MH)*4+1][1] = __builtin_amdgcn_mfma_f32_16x16x32_bf16(aa1, bb1, acc[(MH)*4+1][1], 0, 0, 0); \
    acc[(MH)*4+1][2] = __builtin_amdgcn_mfma_f32_16x16x32_bf16(aa1, bb2, acc[(MH)*4+1][2], 0, 0, 0); \
    acc[(MH)*4+1][3] = __builtin_amdgcn_mfma_f32_16x16x32_bf16(aa1, bb3, acc[(MH)*4+1][3], 0, 0, 0); \
    acc[(MH)*4+2][0] = __builtin_amdgcn_mfma_f32_16x16x32_bf16(aa2, bb0, acc[(MH)*4+2][0], 0, 0, 0); \
    acc[(MH)*4+2][1] = __builtin_amdgcn_mfma_f32_16x16x32_bf16(aa2, bb1, acc[(MH)*4+2][1], 0, 0, 0); \
    acc[(MH)*4+2][2] = __builtin_amdgcn_mfma_f32_16x16x32_bf16(aa2, bb2, acc[(MH)*4+2][2], 0, 0, 0); \
    acc[(MH)*4+2][3] = __builtin_amdgcn_mfma_f32_16x16x32_bf16(aa2, bb3, acc[(MH)*4+2][3], 0, 0, 0); \
    acc[(MH)*4+3][0] = __builtin_amdgcn_mfma_f32_16x16x32_bf16(aa3, bb0, acc[(MH)*4+3][0], 0, 0, 0); \
    acc[(MH)*4+3][1] = __builtin_amdgcn_mfma_f32_16x16x32_bf16(aa3, bb1, acc[(MH)*4+3][1], 0, 0, 0); \
    acc[(MH)*4+3][2] = __builtin_amdgcn_mfma_f32_16x16x32_bf16(aa3, bb2, acc[(MH)*4+3][2], 0, 0, 0); \
    acc[(MH)*4+3][3] = __builtin_amdgcn_mfma_f32_16x16x32_bf16(aa3, bb3, acc[(MH)*4+3][3], 0, 0, 0); \
    __builtin_amdgcn_s_setprio(0); }

// Per K-tile: p0{vmcnt4; stA0; rdB+rdA(mh0); 16mfma} p1{bar; stB0; rdA(mh1); 16mfma}
//             p2{vmcnt4/0; stA1; rdB+rdA(mh0); 16mfma} p3{bar; stB1; rdA(mh1); 16mfma}
#define KTILE(STG, LAST, BC, TN)                                               \
  {                                                                            \
    vm_bar<4>();                                                               \
    if (STG) ST_A(TN, 0)                                                       \
    RD_B4(BC, 0) RD_A4(BC, 0, 0)                                               \
    MM16(0)                                                                    \
    bar();                                                                     \
    if (STG) ST_B(TN, 0)                                                       \
    RD_A4(BC, 0, 1)                                                            \
    MM16(1)                                                                    \
    if (LAST) { vm_bar<0>(); } else { vm_bar<4>(); }                           \
    if (STG) ST_A(TN, 1)                                                       \
    RD_B4(BC, 1) RD_A4(BC, 1, 0)                                               \
    MM16(0)                                                                    \
    bar();                                                                     \
    if (STG) ST_B(TN, 1)                                                       \
    RD_A4(BC, 1, 1)                                                            \
    MM16(1)                                                                    \
  }

__global__ __launch_bounds__(512, 2) void gemm8_kernel(const unsigned short* __restrict__ A,
                                                       const unsigned short* __restrict__ B,
                                                       const float* __restrict__ bias,
                                                       float* __restrict__ C) {
    extern __shared__ __align__(16) unsigned short sm[];   // 128KB dynamic

    const int tid  = threadIdx.x;
    const int lane = tid & 63;
    const int wid  = tid >> 6;
    const int wr   = wid >> 2;       // 0..1 -> 128-row span
    const int wc   = wid & 3;        // 0..3 -> 64-col span

    const int nwg = (TOKENS / BM) * (OUT_F / BN);   // 512, %8==0
    int bid = blockIdx.x;
    int swz = (bid & 7) * (nwg >> 3) + (bid >> 3);  // XCD-aware swizzle
    const int tiles_n = OUT_F / BN;                 // 16
    const int t0 = (swz / tiles_n) * BM;
    const int o0 = (swz % tiles_n) * BN;

    // ---- staging constants (pre-swizzled global source, wave-linear dest) ----
    const int srow = tid >> 2;                      // 0..127
    const int sc   = tid & 3;                       // 8-short chunk
    const int scs  = sc ^ ((srow >> 1) & 3);
    const unsigned short* srcA = A + (size_t)(t0 + srow) * IN_F + scs * 8;
    const unsigned short* srcB = B + (size_t)(o0 + srow) * IN_F + scs * 8;
    const int dstL = srow * 32 + sc * 8;

    // ---- fragment-read bases (shorts), same swizzle ----
    const int l15 = lane & 15, q = lane >> 4;
    const int qe = q ^ ((l15 >> 1) & 3);
    const int a_base = (wr * 128 + l15) * 32 + qe * 8;   // + mh*2048 + mf*512
    const int b_base = (wc * 64 + l15) * 32 + qe * 8;    // + nf*512

    f32x4 acc[8][4];
#pragma unroll
    for (int i = 0; i < 8; ++i)
#pragma unroll
        for (int j = 0; j < 4; ++j) acc[i][j] = (f32x4)0.0f;

    bf16x8 aa0, aa1, aa2, aa3, bb0, bb1, bb2, bb3;

    // ---- prologue: stage tile 0 (8 loads, order A0,B0,A1,B1) ----
    ST_A(0, 0) ST_B(0, 0) ST_A(0, 1) ST_B(0, 1)

#pragma unroll 1
    for (int T = 0; T < NT - 1; ++T) {
        const int bc = T & 1;
        KTILE(true, false, bc, T + 1)
    }
    {   const int bc = (NT - 1) & 1;
        KTILE(false, true, bc, 0)
    }

    // ---- epilogue: C/D layout col = lane&15, row = (lane>>4)*4 + reg ----
    float bv[4];
#pragma unroll
    for (int nf = 0; nf < 4; ++nf) bv[nf] = bias[o0 + wc * 64 + nf * 16 + l15];
#pragma unroll
    for (int mf = 0; mf < 8; ++mf) {
        const int t = t0 + wr * 128 + mf * 16 + q * 4;
#pragma unroll
        for (int nf = 0; nf < 4; ++nf) {
            const int o = o0 + wc * 64 + nf * 16 + l15;
#pragma unroll
            for (int r = 0; r < 4; ++r)
                C[(size_t)(t + r) * OUT_F + o] = acc[mf][nf][r] + bv[nf];
        }
    }
}

// ---------------- fp32 fallback (only if ws too small) ----------------
__global__ __launch_bounds__(256) void gemm_f32_fallback(const float* __restrict__ x,
                                                         const float* __restrict__ w,
                                                         const float* __restrict__ bias,
                                                         const int* __restrict__ mask,
                                                         float* __restrict__ out) {
    __shared__ float As[64][17];
    __shared__ float Bs[64][17];
    int bid = blockIdx.x;
    const int tiles_n = OUT_F / 64;
    int tm = bid / tiles_n, tn = bid % tiles_n;
    int t0 = tm * 64, o0 = tn * 64;
    int tid = threadIdx.x;
    int tx = tid & 15, ty = tid >> 4;
    int lrow = tid >> 2, lc4 = (tid & 3) * 4;
    float acc[4][4] = {};
    for (int k0 = 0; k0 < IN_F; k0 += 16) {
        float4 av = *(const float4*)&x[(size_t)(t0 + lrow) * IN_F + k0 + lc4];
        float4 bv = *(const float4*)&w[(size_t)(o0 + lrow) * IN_F + k0 + lc4];
        int mb = mask[((o0 + lrow) >> 4) * (IN_F / 16) + ((k0 + lc4) >> 4)];
        float s = mb ? 2.0f : 1.0f;
        As[lrow][lc4 + 0] = av.x; As[lrow][lc4 + 1] = av.y;
        As[lrow][lc4 + 2] = av.z; As[lrow][lc4 + 3] = av.w;
        Bs[lrow][lc4 + 0] = bv.x * s; Bs[lrow][lc4 + 1] = bv.y * s;
        Bs[lrow][lc4 + 2] = bv.z * s; Bs[lrow][lc4 + 3] = bv.w * s;
        __syncthreads();
#pragma unroll
        for (int kk = 0; kk < 16; ++kk) {
            float av2[4], bv2[4];
#pragma unroll
            for (int i = 0; i < 4; ++i) av2[i] = As[ty * 4 + i][kk];
#pragma unroll
            for (int j = 0; j < 4; ++j) bv2[j] = Bs[tx * 4 + j][kk];
#pragma unroll
            for (int i = 0; i < 4; ++i)
#pragma unroll
                for (int j = 0; j < 4; ++j) acc[i][j] += av2[i] * bv2[j];
        }
        __syncthreads();
    }
#pragma unroll
    for (int j = 0; j < 4; ++j) {
        int o = o0 + tx * 4 + j;
        float bv = bias[o];
#pragma unroll
        for (int i = 0; i < 4; ++i)
            out[(size_t)(t0 + ty * 4 + i) * OUT_F + o] = acc[i][j] + bv;
    }
}

extern "C" void kernel_launch(void* const* d_in, const int* in_sizes, int n_in,
                              void* d_out, int out_size, void* d_ws, size_t ws_size,
                              hipStream_t stream) {
    const float* x    = (const float*)d_in[0];
    const float* wgt  = (const float*)d_in[1];
    const float* bias = (const float*)d_in[2];
    const int*   mask = (const int*)d_in[3];
    float* out = (float*)d_out;

    size_t xb_bytes = (size_t)TOKENS * IN_F * 2;
    size_t wb_bytes = (size_t)OUT_F * IN_F * 2;

    if (ws_size >= xb_bytes + wb_bytes) {
        unsigned short* xb = (unsigned short*)d_ws;
        unsigned short* wb = (unsigned short*)((char*)d_ws + xb_bytes);
        hipLaunchKernelGGL(cvt_kernel, dim3(XBLOCKS + WBLOCKS), dim3(256), 0, stream,
                           x, wgt, mask, xb, wb);
        (void)hipFuncSetAttribute((const void*)gemm8_kernel,
                                  hipFuncAttributeMaxDynamicSharedMemorySize, 131072);
        hipLaunchKernelGGL(gemm8_kernel, dim3((TOKENS / BM) * (OUT_F / BN)), dim3(512),
                           131072, stream, xb, wb, bias, out);
    } else {
        hipLaunchKernelGGL(gemm_f32_fallback, dim3((TOKENS / 64) * (OUT_F / 64)), dim3(256), 0, stream,
                           x, wgt, bias, mask, out);
    }
}

// Round 7
// 288.773 us; speedup vs baseline: 1.1216x; 1.0094x over previous
//
#include <hip/hip_runtime.h>
#include <hip/hip_bf16.h>
#include <stdint.h>

#define TOKENS 8192
#define IN_F   4096
#define OUT_F  4096

typedef __attribute__((ext_vector_type(4))) float  f32x4;
typedef __attribute__((ext_vector_type(8))) __bf16 bf16x8;

__device__ __forceinline__ unsigned short f2bf(float f) {
    union { float f; uint32_t u; } c; c.f = f;
    uint32_t u = c.u;
    u += 0x7fffu + ((u >> 16) & 1);   // round-to-nearest-even
    return (unsigned short)(u >> 16);
}

__device__ __forceinline__ void load_lds_16(const void* gptr, void* lptr) {
    __builtin_amdgcn_global_load_lds(
        (const __attribute__((address_space(1))) unsigned int*)gptr,
        (__attribute__((address_space(3))) unsigned int*)lptr, 16, 0, 0);
}

template<int N> __device__ __forceinline__ void vm_bar() {
    if constexpr (N == 4) asm volatile("s_waitcnt vmcnt(4)\ns_barrier" ::: "memory");
    else                  asm volatile("s_waitcnt vmcnt(0)\ns_barrier" ::: "memory");
}
// counted DS wait: oldest reads done, newer reads stay in flight under MFMA.
// rule #18: sched_barrier(0) so reg-only MFMAs can't hoist above the wait.
template<int N> __device__ __forceinline__ void lgkm() {
    if constexpr (N == 8)      asm volatile("s_waitcnt lgkmcnt(8)" ::: "memory");
    else if constexpr (N == 4) asm volatile("s_waitcnt lgkmcnt(4)" ::: "memory");
    else                       asm volatile("s_waitcnt lgkmcnt(0)" ::: "memory");
    __builtin_amdgcn_sched_barrier(0);
}

// ---------------- merged prep: x->bf16 and W_eff=W*(1+mask)->bf16 ----------------
#define XBLOCKS 2048
#define WBLOCKS 1024
__global__ __launch_bounds__(256) void cvt_kernel(const float* __restrict__ x,
                                                  const float* __restrict__ w,
                                                  const int* __restrict__ mask,
                                                  unsigned short* __restrict__ xb,
                                                  unsigned short* __restrict__ wb) {
    int b = blockIdx.x;
    if (b < XBLOCKS) {
        const int n4 = TOKENS * IN_F / 4;
        int i = b * 256 + threadIdx.x;
        const int stride = XBLOCKS * 256;
        for (; i < n4; i += stride) {
            float4 v = ((const float4*)x)[i];
            ushort4 o;
            o.x = f2bf(v.x); o.y = f2bf(v.y); o.z = f2bf(v.z); o.w = f2bf(v.w);
            ((ushort4*)xb)[i] = o;
        }
    } else {
        const int n4 = OUT_F * IN_F / 4;
        int i = (b - XBLOCKS) * 256 + threadIdx.x;
        const int stride = WBLOCKS * 256;
        for (; i < n4; i += stride) {
            int elem = i * 4;
            int o = elem >> 12;
            int k = elem & (IN_F - 1);
            int mb = mask[(o >> 4) * (IN_F / 16) + (k >> 4)];
            float s = mb ? 2.0f : 1.0f;
            float4 v = ((const float4*)w)[i];
            ushort4 ov;
            ov.x = f2bf(v.x * s); ov.y = f2bf(v.y * s);
            ov.z = f2bf(v.z * s); ov.w = f2bf(v.w * s);
            ((ushort4*)wb)[i] = ov;
        }
    }
}

// ------- 256x256 8-wave, 4 phases/K-tile, ds-read-ahead by one phase -------
// LDS (shorts): A[buf][ks] at buf*16384 + ks*8192 (256 rows x 32 shorts)
//               B[buf][ks] at 32768 + buf*16384 + ks*8192
// Swizzle: 8-short chunk c XOR (row>>1)&3 (pre-swizzled global source on
// stage, same XOR on fragment read) -> <=2-way banks (free). Measured 0
// conflicts in R3-R6.
#define BM 256
#define BN 256
#define BK 64
#define NT (IN_F / BK)   // 64

#define ST_A(T, H) {                                                           \
    const unsigned short* s_ = srcA + (size_t)(T) * BK + (H) * 32;             \
    unsigned short* d_ = sm + (((T) & 1) * 16384 + (H) * 8192) + dstL;         \
    load_lds_16(s_, d_);                                                       \
    load_lds_16(s_ + (size_t)128 * IN_F, d_ + 4096); }
#define ST_B(T, H) {                                                           \
    const unsigned short* s_ = srcB + (size_t)(T) * BK + (H) * 32;             \
    unsigned short* d_ = sm + (32768 + ((T) & 1) * 16384 + (H) * 8192) + dstL; \
    load_lds_16(s_, d_);                                                       \
    load_lds_16(s_ + (size_t)128 * IN_F, d_ + 4096); }

#define RDB4(R0, R1, R2, R3, BUF, KS) {                                        \
    const unsigned short* p_ = sm + 32768 + (BUF) * 16384 + (KS) * 8192 + b_base; \
    R0 = *(const bf16x8*)(p_);        R1 = *(const bf16x8*)(p_ + 512);         \
    R2 = *(const bf16x8*)(p_ + 1024); R3 = *(const bf16x8*)(p_ + 1536); }

#define RDA4(R0, R1, R2, R3, BUF, KS, MH) {                                    \
    const unsigned short* p_ = sm + (BUF) * 16384 + (KS) * 8192 + (MH) * 2048 + a_base; \
    R0 = *(const bf16x8*)(p_);        R1 = *(const bf16x8*)(p_ + 512);         \
    R2 = *(const bf16x8*)(p_ + 1024); R3 = *(const bf16x8*)(p_ + 1536); }

#define MM16(A0, A1, A2, A3, B0, B1, B2, B3, MH) {                             \
    __builtin_amdgcn_s_setprio(1);                                             \
    acc[(MH)*4+0][0] = __builtin_amdgcn_mfma_f32_16x16x32_bf16(A0, B0, acc[(MH)*4+0][0], 0, 0, 0); \
    acc[(MH)*4+0][1] = __builtin_amdgcn_mfma_f32_16x16x32_bf16(A0, B1, acc[(MH)*4+0][1], 0, 0, 0); \
    acc[(MH)*4+0][2] = __builtin_amdgcn_mfma_f32_16x16x32_bf16(A0, B2, acc[(MH)*4+0][2], 0, 0, 0); \
    acc[(MH)*4+0][3] = __builtin_amdgcn_mfma_f32_16x16x32_bf16(A0, B3, acc[(MH)*4+0][3], 0, 0, 0); \
    acc[(MH)*4+1][0] = __builtin_amdgcn_mfma_f32_16x16x32_bf16(A1, B0, acc[(MH)*4+1][0], 0, 0, 0); \
    acc[(MH)*4+1][1] = __builtin_amdgcn_mfma_f32_16x16x32_bf16(A1, B1, acc[(MH)*4+1][1], 0, 0, 0); \
    acc[(MH)*4+1][2] = __builtin_amdgcn_mfma_f32_16x16x32_bf16(A1, B2, acc[(MH)*4+1][2], 0, 0, 0); \
    acc[(MH)*4+1][3] = __builtin_amdgcn_mfma_f32_16x16x32_bf16(A1, B3, acc[(MH)*4+1][3], 0, 0, 0); \
    acc[(MH)*4+2][0] = __builtin_amdgcn_mfma_f32_16x16x32_bf16(A2, B0, acc[(MH)*4+2][0], 0, 0, 0); \
    acc[(MH)*4+2][1] = __builtin_amdgcn_mfma_f32_16x16x32_bf16(A2, B1, acc[(MH)*4+2][1], 0, 0, 0); \
    acc[(MH)*4+2][2] = __builtin_amdgcn_mfma_f32_16x16x32_bf16(A2, B2, acc[(MH)*4+2][2], 0, 0, 0); \
    acc[(MH)*4+2][3] = __builtin_amdgcn_mfma_f32_16x16x32_bf16(A2, B3, acc[(MH)*4+2][3], 0, 0, 0); \
    acc[(MH)*4+3][0] = __builtin_amdgcn_mfma_f32_16x16x32_bf16(A3, B0, acc[(MH)*4+3][0], 0, 0, 0); \
    acc[(MH)*4+3][1] = __builtin_amdgcn_mfma_f32_16x16x32_bf16(A3, B1, acc[(MH)*4+3][1], 0, 0, 0); \
    acc[(MH)*4+3][2] = __builtin_amdgcn_mfma_f32_16x16x32_bf16(A3, B2, acc[(MH)*4+3][2], 0, 0, 0); \
    acc[(MH)*4+3][3] = __builtin_amdgcn_mfma_f32_16x16x32_bf16(A3, B3, acc[(MH)*4+3][3], 0, 0, 0); \
    __builtin_amdgcn_s_setprio(0); }

__global__ __launch_bounds__(512, 2) void gemm8_kernel(const unsigned short* __restrict__ A,
                                                       const unsigned short* __restrict__ B,
                                                       const float* __restrict__ bias,
                                                       float* __restrict__ C) {
    extern __shared__ __align__(16) unsigned short sm[];   // 128KB dynamic

    const int tid  = threadIdx.x;
    const int lane = tid & 63;
    const int wid  = tid >> 6;
    const int wr   = wid >> 2;       // 0..1 -> 128-row span
    const int wc   = wid & 3;        // 0..3 -> 64-col span

    const int nwg = (TOKENS / BM) * (OUT_F / BN);   // 512, %8==0
    int bid = blockIdx.x;
    int swz = (bid & 7) * (nwg >> 3) + (bid >> 3);  // XCD-aware swizzle
    const int tiles_n = OUT_F / BN;                 // 16
    const int t0 = (swz / tiles_n) * BM;
    const int o0 = (swz % tiles_n) * BN;

    // ---- staging constants (pre-swizzled global source, wave-linear dest) ----
    const int srow = tid >> 2;                      // 0..127
    const int sc   = tid & 3;                       // 8-short chunk
    const int scs  = sc ^ ((srow >> 1) & 3);
    const unsigned short* srcA = A + (size_t)(t0 + srow) * IN_F + scs * 8;
    const unsigned short* srcB = B + (size_t)(o0 + srow) * IN_F + scs * 8;
    const int dstL = srow * 32 + sc * 8;

    // ---- fragment-read bases (shorts), same swizzle ----
    const int l15 = lane & 15, q = lane >> 4;
    const int qe = q ^ ((l15 >> 1) & 3);
    const int a_base = (wr * 128 + l15) * 32 + qe * 8;   // + mh*2048 + mf*512
    const int b_base = (wc * 64 + l15) * 32 + qe * 8;    // + nf*512

    f32x4 acc[8][4];
#pragma unroll
    for (int i = 0; i < 8; ++i)
#pragma unroll
        for (int j = 0; j < 4; ++j) acc[i][j] = (f32x4)0.0f;

    bf16x8 aaE0, aaE1, aaE2, aaE3, aaO0, aaO1, aaO2, aaO3;
    bf16x8 bbE0, bbE1, bbE2, bbE3, bbO0, bbO1, bbO2, bbO3;

    // ---- prologue: stage tile 0 (order A0,B0,A1,B1), guard, prime reads_p0 ----
    ST_A(0, 0) ST_B(0, 0) ST_A(0, 1) ST_B(0, 1)
    vm_bar<4>();                               // A0,B0 of tile0 landed
    RDB4(bbE0, bbE1, bbE2, bbE3, 0, 0)
    RDA4(aaE0, aaE1, aaE2, aaE3, 0, 0, 0)

#pragma unroll 1
    for (int T = 0; T < NT - 1; ++T) {
        const int bc = T & 1, nbc = bc ^ 1;
        // p0: MFMA(ks0,mh0) | readahead A(ks0,mh1) | stage A0(T+1)
        ST_A(T + 1, 0)
        RDA4(aaO0, aaO1, aaO2, aaO3, bc, 0, 1)
        lgkm<4>();
        MM16(aaE0, aaE1, aaE2, aaE3, bbE0, bbE1, bbE2, bbE3, 0)
        // p1: MFMA(ks0,mh1) | guard ks1 | readahead B(ks1)+A(ks1,mh0) | stage B0(T+1)
        ST_B(T + 1, 0)
        vm_bar<4>();                           // tile T's A1,B1 landed
        RDB4(bbO0, bbO1, bbO2, bbO3, bc, 1)
        RDA4(aaE0, aaE1, aaE2, aaE3, bc, 1, 0)
        lgkm<8>();
        MM16(aaO0, aaO1, aaO2, aaO3, bbE0, bbE1, bbE2, bbE3, 1)
        // p2: MFMA(ks1,mh0) | readahead A(ks1,mh1) | stage A1(T+1)
        ST_A(T + 1, 1)
        RDA4(aaO0, aaO1, aaO2, aaO3, bc, 1, 1)
        lgkm<4>();
        MM16(aaE0, aaE1, aaE2, aaE3, bbO0, bbO1, bbO2, bbO3, 0)
        // p3: MFMA(ks1,mh1) | guard T+1 ks0 | readahead next tile p0 | stage B1(T+1)
        ST_B(T + 1, 1)
        vm_bar<4>();                           // tile T+1's A0,B0 landed
        RDB4(bbE0, bbE1, bbE2, bbE3, nbc, 0)
        RDA4(aaE0, aaE1, aaE2, aaE3, nbc, 0, 0)
        lgkm<8>();
        MM16(aaO0, aaO1, aaO2, aaO3, bbO0, bbO1, bbO2, bbO3, 1)
    }
    {   // peeled last tile (bc = 1, no staging)
        RDA4(aaO0, aaO1, aaO2, aaO3, 1, 0, 1)
        lgkm<4>();
        MM16(aaE0, aaE1, aaE2, aaE3, bbE0, bbE1, bbE2, bbE3, 0)
        vm_bar<0>();                           // last tile's A1,B1 landed
        RDB4(bbO0, bbO1, bbO2, bbO3, 1, 1)
        RDA4(aaE0, aaE1, aaE2, aaE3, 1, 1, 0)
        lgkm<8>();
        MM16(aaO0, aaO1, aaO2, aaO3, bbE0, bbE1, bbE2, bbE3, 1)
        RDA4(aaO0, aaO1, aaO2, aaO3, 1, 1, 1)
        lgkm<4>();
        MM16(aaE0, aaE1, aaE2, aaE3, bbO0, bbO1, bbO2, bbO3, 0)
        lgkm<0>();
        MM16(aaO0, aaO1, aaO2, aaO3, bbO0, bbO1, bbO2, bbO3, 1)
    }

    // ---- epilogue: C/D layout col = lane&15, row = (lane>>4)*4 + reg ----
    float bv[4];
#pragma unroll
    for (int nf = 0; nf < 4; ++nf) bv[nf] = bias[o0 + wc * 64 + nf * 16 + l15];
#pragma unroll
    for (int mf = 0; mf < 8; ++mf) {
        const int t = t0 + wr * 128 + mf * 16 + q * 4;
#pragma unroll
        for (int nf = 0; nf < 4; ++nf) {
            const int o = o0 + wc * 64 + nf * 16 + l15;
#pragma unroll
            for (int r = 0; r < 4; ++r)
                C[(size_t)(t + r) * OUT_F + o] = acc[mf][nf][r] + bv[nf];
        }
    }
}

// ---------------- fp32 fallback (only if ws too small) ----------------
__global__ __launch_bounds__(256) void gemm_f32_fallback(const float* __restrict__ x,
                                                         const float* __restrict__ w,
                                                         const float* __restrict__ bias,
                                                         const int* __restrict__ mask,
                                                         float* __restrict__ out) {
    __shared__ float As[64][17];
    __shared__ float Bs[64][17];
    int bid = blockIdx.x;
    const int tiles_n = OUT_F / 64;
    int tm = bid / tiles_n, tn = bid % tiles_n;
    int t0 = tm * 64, o0 = tn * 64;
    int tid = threadIdx.x;
    int tx = tid & 15, ty = tid >> 4;
    int lrow = tid >> 2, lc4 = (tid & 3) * 4;
    float acc[4][4] = {};
    for (int k0 = 0; k0 < IN_F; k0 += 16) {
        float4 av = *(const float4*)&x[(size_t)(t0 + lrow) * IN_F + k0 + lc4];
        float4 bv = *(const float4*)&w[(size_t)(o0 + lrow) * IN_F + k0 + lc4];
        int mb = mask[((o0 + lrow) >> 4) * (IN_F / 16) + ((k0 + lc4) >> 4)];
        float s = mb ? 2.0f : 1.0f;
        As[lrow][lc4 + 0] = av.x; As[lrow][lc4 + 1] = av.y;
        As[lrow][lc4 + 2] = av.z; As[lrow][lc4 + 3] = av.w;
        Bs[lrow][lc4 + 0] = bv.x * s; Bs[lrow][lc4 + 1] = bv.y * s;
        Bs[lrow][lc4 + 2] = bv.z * s; Bs[lrow][lc4 + 3] = bv.w * s;
        __syncthreads();
#pragma unroll
        for (int kk = 0; kk < 16; ++kk) {
            float av2[4], bv2[4];
#pragma unroll
            for (int i = 0; i < 4; ++i) av2[i] = As[ty * 4 + i][kk];
#pragma unroll
            for (int j = 0; j < 4; ++j) bv2[j] = Bs[tx * 4 + j][kk];
#pragma unroll
            for (int i = 0; i < 4; ++i)
#pragma unroll
                for (int j = 0; j < 4; ++j) acc[i][j] += av2[i] * bv2[j];
        }
        __syncthreads();
    }
#pragma unroll
    for (int j = 0; j < 4; ++j) {
        int o = o0 + tx * 4 + j;
        float bv = bias[o];
#pragma unroll
        for (int i = 0; i < 4; ++i)
            out[(size_t)(t0 + ty * 4 + i) * OUT_F + o] = acc[i][j] + bv;
    }
}

extern "C" void kernel_launch(void* const* d_in, const int* in_sizes, int n_in,
                              void* d_out, int out_size, void* d_ws, size_t ws_size,
                              hipStream_t stream) {
    const float* x    = (const float*)d_in[0];
    const float* wgt  = (const float*)d_in[1];
    const float* bias = (const float*)d_in[2];
    const int*   mask = (const int*)d_in[3];
    float* out = (float*)d_out;

    size_t xb_bytes = (size_t)TOKENS * IN_F * 2;
    size_t wb_bytes = (size_t)OUT_F * IN_F * 2;

    if (ws_size >= xb_bytes + wb_bytes) {
        unsigned short* xb = (unsigned short*)d_ws;
        unsigned short* wb = (unsigned short*)((char*)d_ws + xb_bytes);
        hipLaunchKernelGGL(cvt_kernel, dim3(XBLOCKS + WBLOCKS), dim3(256), 0, stream,
                           x, wgt, mask, xb, wb);
        (void)hipFuncSetAttribute((const void*)gemm8_kernel,
                                  hipFuncAttributeMaxDynamicSharedMemorySize, 131072);
        hipLaunchKernelGGL(gemm8_kernel, dim3((TOKENS / BM) * (OUT_F / BN)), dim3(512),
                           131072, stream, xb, wb, bias, out);
    } else {
        hipLaunchKernelGGL(gemm_f32_fallback, dim3((TOKENS / 64) * (OUT_F / 64)), dim3(256), 0, stream,
                           x, wgt, bias, mask, out);
    }
}

// Round 8
// 287.913 us; speedup vs baseline: 1.1249x; 1.0030x over previous
//
#include <hip/hip_runtime.h>
#include <hip/hip_bf16.h>
#include <stdint.h>

#define TOKENS 8192
#define IN_F   4096
#define OUT_F  4096

typedef __attribute__((ext_vector_type(4))) float  f32x4;
typedef __attribute__((ext_vector_type(8))) __bf16 bf16x8;

__device__ __forceinline__ unsigned short f2bf(float f) {
    union { float f; uint32_t u; } c; c.f = f;
    uint32_t u = c.u;
    u += 0x7fffu + ((u >> 16) & 1);   // round-to-nearest-even
    return (unsigned short)(u >> 16);
}

__device__ __forceinline__ void load_lds_16(const void* gptr, void* lptr) {
    __builtin_amdgcn_global_load_lds(
        (const __attribute__((address_space(1))) unsigned int*)gptr,
        (__attribute__((address_space(3))) unsigned int*)lptr, 16, 0, 0);
}

template<int N> __device__ __forceinline__ void vm_bar() {
    if constexpr (N == 4) asm volatile("s_waitcnt vmcnt(4)\ns_barrier" ::: "memory");
    else                  asm volatile("s_waitcnt vmcnt(0)\ns_barrier" ::: "memory");
}
// counted DS wait: oldest reads done, newer stay in flight under MFMA.
// rule #18: sched_barrier(0) so reg-only MFMAs can't hoist above the wait.
template<int N> __device__ __forceinline__ void lgkm() {
    if constexpr (N == 8)      asm volatile("s_waitcnt lgkmcnt(8)" ::: "memory");
    else if constexpr (N == 4) asm volatile("s_waitcnt lgkmcnt(4)" ::: "memory");
    else                       asm volatile("s_waitcnt lgkmcnt(0)" ::: "memory");
    __builtin_amdgcn_sched_barrier(0);
}

// ---------------- merged prep: x->bf16 and W_eff=W*(1+mask)->bf16 ----------------
#define XBLOCKS 2048
#define WBLOCKS 1024
__global__ __launch_bounds__(256) void cvt_kernel(const float* __restrict__ x,
                                                  const float* __restrict__ w,
                                                  const int* __restrict__ mask,
                                                  unsigned short* __restrict__ xb,
                                                  unsigned short* __restrict__ wb) {
    int b = blockIdx.x;
    if (b < XBLOCKS) {
        const int n4 = TOKENS * IN_F / 4;
        int i = b * 256 + threadIdx.x;
        const int stride = XBLOCKS * 256;
        for (; i < n4; i += stride) {
            float4 v = ((const float4*)x)[i];
            ushort4 o;
            o.x = f2bf(v.x); o.y = f2bf(v.y); o.z = f2bf(v.z); o.w = f2bf(v.w);
            ((ushort4*)xb)[i] = o;
        }
    } else {
        const int n4 = OUT_F * IN_F / 4;
        int i = (b - XBLOCKS) * 256 + threadIdx.x;
        const int stride = WBLOCKS * 256;
        for (; i < n4; i += stride) {
            int elem = i * 4;
            int o = elem >> 12;
            int k = elem & (IN_F - 1);
            int mb = mask[(o >> 4) * (IN_F / 16) + (k >> 4)];
            float s = mb ? 2.0f : 1.0f;
            float4 v = ((const float4*)w)[i];
            ushort4 ov;
            ov.x = f2bf(v.x * s); ov.y = f2bf(v.y * s);
            ov.z = f2bf(v.z * s); ov.w = f2bf(v.w * s);
            ((ushort4*)wb)[i] = ov;
        }
    }
}

// ------- 256x256 8-wave, 4 phases/K-tile, read-ahead, const-folded bufs -------
// LDS (shorts): A[buf][ks] at buf*16384 + ks*8192 (256 rows x 32 shorts)
//               B[buf][ks] at 32768 + buf*16384 + ks*8192
// Swizzle: 8-short chunk c XOR (row>>1)&3 (pre-swizzled global source on
// stage, same XOR on fragment read) -> measured-0 conflicts (R3-R7).
#define BM 256
#define BN 256
#define BK 64
#define NT (IN_F / BK)   // 64

// SOFF/BUF/H all compile-time: global imm-offset + LDS const base fold.
#define ST_A(SOFF, BUF, H) {                                                   \
    const unsigned short* s_ = srcA + (SOFF) + (H) * 32;                       \
    unsigned short* d_ = sm + ((BUF) * 16384 + (H) * 8192) + dstL;             \
    load_lds_16(s_, d_);                                                       \
    load_lds_16(s_ + (size_t)128 * IN_F, d_ + 4096); }
#define ST_B(SOFF, BUF, H) {                                                   \
    const unsigned short* s_ = srcB + (SOFF) + (H) * 32;                       \
    unsigned short* d_ = sm + (32768 + (BUF) * 16384 + (H) * 8192) + dstL;     \
    load_lds_16(s_, d_);                                                       \
    load_lds_16(s_ + (size_t)128 * IN_F, d_ + 4096); }

#define RDB4(R0, R1, R2, R3, BUF, KS) {                                        \
    const unsigned short* p_ = pb_base + ((BUF) * 16384 + (KS) * 8192);        \
    R0 = *(const bf16x8*)(p_);        R1 = *(const bf16x8*)(p_ + 512);         \
    R2 = *(const bf16x8*)(p_ + 1024); R3 = *(const bf16x8*)(p_ + 1536); }

#define RDA4(R0, R1, R2, R3, BUF, KS, MH) {                                    \
    const unsigned short* p_ = pa_base + ((BUF) * 16384 + (KS) * 8192 + (MH) * 2048); \
    R0 = *(const bf16x8*)(p_);        R1 = *(const bf16x8*)(p_ + 512);         \
    R2 = *(const bf16x8*)(p_ + 1024); R3 = *(const bf16x8*)(p_ + 1536); }

#define MM16(A0, A1, A2, A3, B0, B1, B2, B3, MH) {                             \
    __builtin_amdgcn_s_setprio(1);                                             \
    acc[(MH)*4+0][0] = __builtin_amdgcn_mfma_f32_16x16x32_bf16(A0, B0, acc[(MH)*4+0][0], 0, 0, 0); \
    acc[(MH)*4+0][1] = __builtin_amdgcn_mfma_f32_16x16x32_bf16(A0, B1, acc[(MH)*4+0][1], 0, 0, 0); \
    acc[(MH)*4+0][2] = __builtin_amdgcn_mfma_f32_16x16x32_bf16(A0, B2, acc[(MH)*4+0][2], 0, 0, 0); \
    acc[(MH)*4+0][3] = __builtin_amdgcn_mfma_f32_16x16x32_bf16(A0, B3, acc[(MH)*4+0][3], 0, 0, 0); \
    acc[(MH)*4+1][0] = __builtin_amdgcn_mfma_f32_16x16x32_bf16(A1, B0, acc[(MH)*4+1][0], 0, 0, 0); \
    acc[(MH)*4+1][1] = __builtin_amdgcn_mfma_f32_16x16x32_bf16(A1, B1, acc[(MH)*4+1][1], 0, 0, 0); \
    acc[(MH)*4+1][2] = __builtin_amdgcn_mfma_f32_16x16x32_bf16(A1, B2, acc[(MH)*4+1][2], 0, 0, 0); \
    acc[(MH)*4+1][3] = __builtin_amdgcn_mfma_f32_16x16x32_bf16(A1, B3, acc[(MH)*4+1][3], 0, 0, 0); \
    acc[(MH)*4+2][0] = __builtin_amdgcn_mfma_f32_16x16x32_bf16(A2, B0, acc[(MH)*4+2][0], 0, 0, 0); \
    acc[(MH)*4+2][1] = __builtin_amdgcn_mfma_f32_16x16x32_bf16(A2, B1, acc[(MH)*4+2][1], 0, 0, 0); \
    acc[(MH)*4+2][2] = __builtin_amdgcn_mfma_f32_16x16x32_bf16(A2, B2, acc[(MH)*4+2][2], 0, 0, 0); \
    acc[(MH)*4+2][3] = __builtin_amdgcn_mfma_f32_16x16x32_bf16(A2, B3, acc[(MH)*4+2][3], 0, 0, 0); \
    acc[(MH)*4+3][0] = __builtin_amdgcn_mfma_f32_16x16x32_bf16(A3, B0, acc[(MH)*4+3][0], 0, 0, 0); \
    acc[(MH)*4+3][1] = __builtin_amdgcn_mfma_f32_16x16x32_bf16(A3, B1, acc[(MH)*4+3][1], 0, 0, 0); \
    acc[(MH)*4+3][2] = __builtin_amdgcn_mfma_f32_16x16x32_bf16(A3, B2, acc[(MH)*4+3][2], 0, 0, 0); \
    acc[(MH)*4+3][3] = __builtin_amdgcn_mfma_f32_16x16x32_bf16(A3, B3, acc[(MH)*4+3][3], 0, 0, 0); \
    __builtin_amdgcn_s_setprio(0); }

// One K-tile, BC = compile-time buffer parity. Stages tile at srcA+SOFF into
// buffer BC^1. Waits identical to R7 (accounting verified there).
#define KT(BC, SOFF)                                                           \
  {                                                                            \
    ST_A(SOFF, (BC)^1, 0)                                                      \
    RDA4(aaO0, aaO1, aaO2, aaO3, BC, 0, 1)                                     \
    lgkm<4>();                                                                 \
    MM16(aaE0, aaE1, aaE2, aaE3, bbE0, bbE1, bbE2, bbE3, 0)                    \
    ST_B(SOFF, (BC)^1, 0)                                                      \
    vm_bar<4>();                                                               \
    RDB4(bbO0, bbO1, bbO2, bbO3, BC, 1)                                        \
    RDA4(aaE0, aaE1, aaE2, aaE3, BC, 1, 0)                                     \
    lgkm<8>();                                                                 \
    MM16(aaO0, aaO1, aaO2, aaO3, bbE0, bbE1, bbE2, bbE3, 1)                    \
    ST_A(SOFF, (BC)^1, 1)                                                      \
    RDA4(aaO0, aaO1, aaO2, aaO3, BC, 1, 1)                                     \
    lgkm<4>();                                                                 \
    MM16(aaE0, aaE1, aaE2, aaE3, bbO0, bbO1, bbO2, bbO3, 0)                    \
    ST_B(SOFF, (BC)^1, 1)                                                      \
    vm_bar<4>();                                                               \
    RDB4(bbE0, bbE1, bbE2, bbE3, (BC)^1, 0)                                    \
    RDA4(aaE0, aaE1, aaE2, aaE3, (BC)^1, 0, 0)                                 \
    lgkm<8>();                                                                 \
    MM16(aaO0, aaO1, aaO2, aaO3, bbO0, bbO1, bbO2, bbO3, 1)                    \
  }

__global__ __launch_bounds__(512, 2) void gemm8_kernel(const unsigned short* __restrict__ A,
                                                       const unsigned short* __restrict__ B,
                                                       const float* __restrict__ bias,
                                                       float* __restrict__ C) {
    extern __shared__ __align__(16) unsigned short sm[];   // 128KB dynamic

    const int tid  = threadIdx.x;
    const int lane = tid & 63;
    const int wid  = tid >> 6;
    const int wr   = wid >> 2;       // 0..1 -> 128-row span
    const int wc   = wid & 3;        // 0..3 -> 64-col span

    const int nwg = (TOKENS / BM) * (OUT_F / BN);   // 512, %8==0
    int bid = blockIdx.x;
    int swz = (bid & 7) * (nwg >> 3) + (bid >> 3);  // XCD-aware swizzle
    const int tiles_n = OUT_F / BN;                 // 16
    const int t0 = (swz / tiles_n) * BM;
    const int o0 = (swz % tiles_n) * BN;

    // ---- staging constants (pre-swizzled global source, wave-linear dest) ----
    const int srow = tid >> 2;                      // 0..127
    const int sc   = tid & 3;                       // 8-short chunk
    const int scs  = sc ^ ((srow >> 1) & 3);
    const unsigned short* srcA = A + (size_t)(t0 + srow) * IN_F + scs * 8;
    const unsigned short* srcB = B + (size_t)(o0 + srow) * IN_F + scs * 8;
    const int dstL = srow * 32 + sc * 8;

    // ---- fragment-read base POINTERS (const-offset ds_reads fold off these) ----
    const int l15 = lane & 15, q = lane >> 4;
    const int qe = q ^ ((l15 >> 1) & 3);
    const unsigned short* pa_base = sm + (wr * 128 + l15) * 32 + qe * 8;
    const unsigned short* pb_base = sm + 32768 + (wc * 64 + l15) * 32 + qe * 8;

    f32x4 acc[8][4];
#pragma unroll
    for (int i = 0; i < 8; ++i)
#pragma unroll
        for (int j = 0; j < 4; ++j) acc[i][j] = (f32x4)0.0f;

    bf16x8 aaE0, aaE1, aaE2, aaE3, aaO0, aaO1, aaO2, aaO3;
    bf16x8 bbE0, bbE1, bbE2, bbE3, bbO0, bbO1, bbO2, bbO3;

    // ---- prologue: stage tile 0 into buf0 (order A0,B0,A1,B1), prime E ----
    ST_A(0, 0, 0) ST_B(0, 0, 0) ST_A(0, 0, 1) ST_B(0, 0, 1)
    vm_bar<4>();                               // A0,B0 of tile0 landed
    RDB4(bbE0, bbE1, bbE2, bbE3, 0, 0)
    RDA4(aaE0, aaE1, aaE2, aaE3, 0, 0, 0)

    // tiles 0..61 (31 iters x 2), then tile 62, then peeled 63.
#pragma unroll 1
    for (int i = 0; i < (NT - 2) / 2; ++i) {   // 31 iterations
        KT(0, 64)      // compute even tile, stage odd tile -> buf1
        KT(1, 128)     // compute odd tile, stage even tile -> buf0
        srcA += 128; srcB += 128;
    }
    KT(0, 64)          // tile 62 (buf0), stages tile 63 -> buf1
    {   // peeled tile 63 (buf1, no staging) — waits as R7's verified drain
        RDA4(aaO0, aaO1, aaO2, aaO3, 1, 0, 1)
        lgkm<4>();
        MM16(aaE0, aaE1, aaE2, aaE3, bbE0, bbE1, bbE2, bbE3, 0)
        vm_bar<0>();                           // tile 63's A1,B1 landed
        RDB4(bbO0, bbO1, bbO2, bbO3, 1, 1)
        RDA4(aaE0, aaE1, aaE2, aaE3, 1, 1, 0)
        lgkm<8>();
        MM16(aaO0, aaO1, aaO2, aaO3, bbE0, bbE1, bbE2, bbE3, 1)
        RDA4(aaO0, aaO1, aaO2, aaO3, 1, 1, 1)
        lgkm<4>();
        MM16(aaE0, aaE1, aaE2, aaE3, bbO0, bbO1, bbO2, bbO3, 0)
        lgkm<0>();
        MM16(aaO0, aaO1, aaO2, aaO3, bbO0, bbO1, bbO2, bbO3, 1)
    }

    // ---- epilogue: C/D layout col = lane&15, row = (lane>>4)*4 + reg ----
    float bv[4];
#pragma unroll
    for (int nf = 0; nf < 4; ++nf) bv[nf] = bias[o0 + wc * 64 + nf * 16 + l15];
#pragma unroll
    for (int mf = 0; mf < 8; ++mf) {
        const int t = t0 + wr * 128 + mf * 16 + q * 4;
#pragma unroll
        for (int nf = 0; nf < 4; ++nf) {
            const int o = o0 + wc * 64 + nf * 16 + l15;
#pragma unroll
            for (int r = 0; r < 4; ++r)
                C[(size_t)(t + r) * OUT_F + o] = acc[mf][nf][r] + bv[nf];
        }
    }
}

// ---------------- fp32 fallback (only if ws too small) ----------------
__global__ __launch_bounds__(256) void gemm_f32_fallback(const float* __restrict__ x,
                                                         const float* __restrict__ w,
                                                         const float* __restrict__ bias,
                                                         const int* __restrict__ mask,
                                                         float* __restrict__ out) {
    __shared__ float As[64][17];
    __shared__ float Bs[64][17];
    int bid = blockIdx.x;
    const int tiles_n = OUT_F / 64;
    int tm = bid / tiles_n, tn = bid % tiles_n;
    int t0 = tm * 64, o0 = tn * 64;
    int tid = threadIdx.x;
    int tx = tid & 15, ty = tid >> 4;
    int lrow = tid >> 2, lc4 = (tid & 3) * 4;
    float acc[4][4] = {};
    for (int k0 = 0; k0 < IN_F; k0 += 16) {
        float4 av = *(const float4*)&x[(size_t)(t0 + lrow) * IN_F + k0 + lc4];
        float4 bv = *(const float4*)&w[(size_t)(o0 + lrow) * IN_F + k0 + lc4];
        int mb = mask[((o0 + lrow) >> 4) * (IN_F / 16) + ((k0 + lc4) >> 4)];
        float s = mb ? 2.0f : 1.0f;
        As[lrow][lc4 + 0] = av.x; As[lrow][lc4 + 1] = av.y;
        As[lrow][lc4 + 2] = av.z; As[lrow][lc4 + 3] = av.w;
        Bs[lrow][lc4 + 0] = bv.x * s; Bs[lrow][lc4 + 1] = bv.y * s;
        Bs[lrow][lc4 + 2] = bv.z * s; Bs[lrow][lc4 + 3] = bv.w * s;
        __syncthreads();
#pragma unroll
        for (int kk = 0; kk < 16; ++kk) {
            float av2[4], bv2[4];
#pragma unroll
            for (int i = 0; i < 4; ++i) av2[i] = As[ty * 4 + i][kk];
#pragma unroll
            for (int j = 0; j < 4; ++j) bv2[j] = Bs[tx * 4 + j][kk];
#pragma unroll
            for (int i = 0; i < 4; ++i)
#pragma unroll
                for (int j = 0; j < 4; ++j) acc[i][j] += av2[i] * bv2[j];
        }
        __syncthreads();
    }
#pragma unroll
    for (int j = 0; j < 4; ++j) {
        int o = o0 + tx * 4 + j;
        float bv = bias[o];
#pragma unroll
        for (int i = 0; i < 4; ++i)
            out[(size_t)(t0 + ty * 4 + i) * OUT_F + o] = acc[i][j] + bv;
    }
}

extern "C" void kernel_launch(void* const* d_in, const int* in_sizes, int n_in,
                              void* d_out, int out_size, void* d_ws, size_t ws_size,
                              hipStream_t stream) {
    const float* x    = (const float*)d_in[0];
    const float* wgt  = (const float*)d_in[1];
    const float* bias = (const float*)d_in[2];
    const int*   mask = (const int*)d_in[3];
    float* out = (float*)d_out;

    size_t xb_bytes = (size_t)TOKENS * IN_F * 2;
    size_t wb_bytes = (size_t)OUT_F * IN_F * 2;

    if (ws_size >= xb_bytes + wb_bytes) {
        unsigned short* xb = (unsigned short*)d_ws;
        unsigned short* wb = (unsigned short*)((char*)d_ws + xb_bytes);
        hipLaunchKernelGGL(cvt_kernel, dim3(XBLOCKS + WBLOCKS), dim3(256), 0, stream,
                           x, wgt, mask, xb, wb);
        (void)hipFuncSetAttribute((const void*)gemm8_kernel,
                                  hipFuncAttributeMaxDynamicSharedMemorySize, 131072);
        hipLaunchKernelGGL(gemm8_kernel, dim3((TOKENS / BM) * (OUT_F / BN)), dim3(512),
                           131072, stream, xb, wb, bias, out);
    } else {
        hipLaunchKernelGGL(gemm_f32_fallback, dim3((TOKENS / 64) * (OUT_F / 64)), dim3(256), 0, stream,
                           x, wgt, bias, mask, out);
    }
}